// Round 5
// baseline (95.063 us; speedup 1.0000x reference)
//
#include <hip/hip_runtime.h>
#include <hip/hip_bf16.h>

// Problem: B=256, N=16384, D=7, NUM_CLASSES=3, EPS=1e-6
// Inputs (float32): output [B,N,7], target [B,N,7]. Output: scalar float32.
//
// Best-known main structure (R2: float4 LDS staging, VGPR~20, 8 blocks/CU)
// + fused final reduction via last-block-done (removes 2nd kernel node and
// its launch gap). Counter reset by a tiny in-stream memset (graph-legal).

#define RD 7
#define NRECTOT (256 * 16384)            // 4,194,304 records
#define BLOCK 256
#define GRID 2048                        // 8 iterations per block, exact
#define F4T ((BLOCK * RD) / 4)           // 448 float4 per tensor per tile

__global__ __launch_bounds__(BLOCK) void loss_kernel(
    const float* __restrict__ out, const float* __restrict__ tgt,
    float* __restrict__ partial, unsigned int* __restrict__ counter,
    float* __restrict__ result) {
    __shared__ float4 so4[F4T];
    __shared__ float4 st4[F4T];
    const float* so = (const float*)so4;
    const float* st = (const float*)st4;
    const float4* og = (const float4*)out;
    const float4* tg = (const float4*)tgt;

    float acc = 0.0f;
    const int t = threadIdx.x;

    for (int base = blockIdx.x * BLOCK; base < NRECTOT; base += GRID * BLOCK) {
        // base*RD is always a multiple of 1792 -> divisible by 4.
        const int gbase4 = (base * RD) >> 2;
        __syncthreads();  // previous tile's LDS readers done

        // Stage 448 float4 per tensor, fully coalesced dwordx4.
        so4[t] = og[gbase4 + t];
        st4[t] = tg[gbase4 + t];
        {
            const int idx = BLOCK + t;
            if (idx < F4T) {
                so4[idx] = og[gbase4 + idx];
                st4[idx] = tg[gbase4 + idx];
            }
        }
        __syncthreads();

        // One record per thread. Stride-7 LDS: gcd(7,32)=1 -> conflict-free
        // within 32 lanes; the 2-way 64-lane aliasing is free (m136).
        const float* ro = &so[t * RD];
        const float* rt = &st[t * RD];

        const float p_obj = ro[0];
        const float px = ro[1], py = ro[2], ps = ro[3];
        const float l0 = ro[4], l1 = ro[5], l2 = ro[6];
        const float t_obj = rt[0];
        const float tx = rt[1], ty = rt[2], ts = rt[3];
        const float cls = rt[4];

        const float m = (t_obj > 0.5f) ? 1.0f : 0.0f;

        // box regression
        const float dx = tx - px, dy = ty - py;
        const float dsz = __fsqrt_rn(ts) - __fsqrt_rn(ps);
        const float box = dx * dx + dy * dy + 2.0f * dsz * dsz;

        // IoU of axis-aligned squares
        const float hp = 0.5f * ps, ht = 0.5f * ts;
        const float lx = fmaxf(px - hp, tx - ht);
        const float rx = fminf(px + hp, tx + ht);
        const float ly = fmaxf(py - hp, ty - ht);
        const float ry = fminf(py + hp, ty + ht);
        const float inter = fmaxf(rx - lx, 0.0f) * fmaxf(ry - ly, 0.0f);
        const float uni = ps * ps + ts * ts - inter;
        const float iou = inter / (uni + 1e-6f);

        // shared log terms (p_obj in (0.01,0.99))
        const float logp  = __logf(p_obj);
        const float log1p = __logf(1.0f - p_obj);

        const float bce_obj = -(iou * logp + (1.0f - iou) * log1p);

        // 3-class log-softmax CE
        const float mx = fmaxf(fmaxf(l0, l1), l2);
        const float esum = __expf(l0 - mx) + __expf(l1 - mx) + __expf(l2 - mx);
        const float lse = mx + __logf(esum);
        const float lcls = (cls < 0.5f) ? l0 : ((cls < 1.5f) ? l1 : l2);
        const float ce = lse - lcls;

        const float bce_noobj = -(t_obj * logp + (1.0f - t_obj) * log1p);

        acc += m * (5.0f * box + 2.0f * ce + bce_obj)
             + 1.5f * (1.0f - m) * bce_noobj;
    }

    // block reduce
#pragma unroll
    for (int off = 32; off > 0; off >>= 1) acc += __shfl_down(acc, off);
    __shared__ float wsum[BLOCK / 64];
    __shared__ bool amLast;
    if ((t & 63) == 0) wsum[t >> 6] = acc;
    __syncthreads();
    if (t == 0) {
        float s = wsum[0] + wsum[1] + wsum[2] + wsum[3];
        // publish partial (release via the ACQ_REL fetch_add), count completion
        __hip_atomic_store(&partial[blockIdx.x], s, __ATOMIC_RELAXED,
                           __HIP_MEMORY_SCOPE_AGENT);
        unsigned int old = __hip_atomic_fetch_add(counter, 1u, __ATOMIC_ACQ_REL,
                                                  __HIP_MEMORY_SCOPE_AGENT);
        amLast = (old == GRID - 1);
    }
    __syncthreads();
    if (amLast) {
        // last-finished block: parallel final reduce of GRID partials
        float a = 0.0f;
#pragma unroll
        for (int k = 0; k < GRID / BLOCK; ++k)
            a += __hip_atomic_load(&partial[k * BLOCK + t], __ATOMIC_RELAXED,
                                   __HIP_MEMORY_SCOPE_AGENT);
#pragma unroll
        for (int off = 32; off > 0; off >>= 1) a += __shfl_down(a, off);
        if ((t & 63) == 0) wsum[t >> 6] = a;
        __syncthreads();
        if (t == 0) result[0] = wsum[0] + wsum[1] + wsum[2] + wsum[3];
    }
}

extern "C" void kernel_launch(void* const* d_in, const int* in_sizes, int n_in,
                              void* d_out, int out_size, void* d_ws, size_t ws_size,
                              hipStream_t stream) {
    const float* out = (const float*)d_in[0];  // output [B,N,7]
    const float* tgt = (const float*)d_in[1];  // target [B,N,7]
    float* result = (float*)d_out;

    // d_ws layout: [0..3] counter, [256..] partials (GRID floats)
    unsigned int* counter = (unsigned int*)d_ws;
    float* partial = (float*)((char*)d_ws + 256);

    // reset completion counter each call (ws is NOT re-poisoned between
    // replays and the kernel leaves counter==GRID) -- async, graph-legal
    hipMemsetAsync(counter, 0, sizeof(unsigned int), stream);

    loss_kernel<<<GRID, BLOCK, 0, stream>>>(out, tgt, partial, counter, result);
}

// Round 6
// 62.299 us; speedup vs baseline: 1.5259x; 1.5259x over previous
//
#include <hip/hip_runtime.h>
#include <hip/hip_bf16.h>

// Problem: B=256, N=16384, D=7, NUM_CLASSES=3, EPS=1e-6
// Inputs (float32): output [B,N,7], target [B,N,7]. Output: scalar float32.
//
// R1's proven fabric-roofline main loop (float4 LDS staging, VGPR~20,
// 8 blocks/CU) + tail fused via ONE relaxed float atomicAdd per block
// (no agent-scope ACQ_REL fences -- those caused the R2/R4 2x regression).
// d_out zeroed by an in-stream 4-byte memset node (graph-legal).

#define RD 7
#define NRECTOT (256 * 16384)            // 4,194,304 records
#define BLOCK 256
#define GRID 2048                        // 8 iterations per block, exact
#define F4T ((BLOCK * RD) / 4)           // 448 float4 per tensor per tile

__global__ __launch_bounds__(BLOCK) void loss_kernel(
    const float* __restrict__ out, const float* __restrict__ tgt,
    float* __restrict__ result) {
    __shared__ float4 so4[F4T];
    __shared__ float4 st4[F4T];
    const float* so = (const float*)so4;
    const float* st = (const float*)st4;
    const float4* og = (const float4*)out;
    const float4* tg = (const float4*)tgt;

    float acc = 0.0f;
    const int t = threadIdx.x;

    for (int base = blockIdx.x * BLOCK; base < NRECTOT; base += GRID * BLOCK) {
        // base*RD is always a multiple of 1792 -> divisible by 4.
        const int gbase4 = (base * RD) >> 2;
        __syncthreads();  // previous tile's LDS readers done

        // Stage 448 float4 per tensor, fully coalesced dwordx4.
        so4[t] = og[gbase4 + t];
        st4[t] = tg[gbase4 + t];
        {
            const int idx = BLOCK + t;
            if (idx < F4T) {
                so4[idx] = og[gbase4 + idx];
                st4[idx] = tg[gbase4 + idx];
            }
        }
        __syncthreads();

        // One record per thread. Stride-7 LDS: gcd(7,32)=1 -> conflict-free
        // within 32 lanes; the 2-way 64-lane aliasing is free (m136).
        const float* ro = &so[t * RD];
        const float* rt = &st[t * RD];

        const float p_obj = ro[0];
        const float px = ro[1], py = ro[2], ps = ro[3];
        const float l0 = ro[4], l1 = ro[5], l2 = ro[6];
        const float t_obj = rt[0];
        const float tx = rt[1], ty = rt[2], ts = rt[3];
        const float cls = rt[4];

        const float m = (t_obj > 0.5f) ? 1.0f : 0.0f;

        // box regression
        const float dx = tx - px, dy = ty - py;
        const float dsz = __fsqrt_rn(ts) - __fsqrt_rn(ps);
        const float box = dx * dx + dy * dy + 2.0f * dsz * dsz;

        // IoU of axis-aligned squares
        const float hp = 0.5f * ps, ht = 0.5f * ts;
        const float lx = fmaxf(px - hp, tx - ht);
        const float rx = fminf(px + hp, tx + ht);
        const float ly = fmaxf(py - hp, ty - ht);
        const float ry = fminf(py + hp, ty + ht);
        const float inter = fmaxf(rx - lx, 0.0f) * fmaxf(ry - ly, 0.0f);
        const float uni = ps * ps + ts * ts - inter;
        const float iou = inter / (uni + 1e-6f);

        // shared log terms (p_obj in (0.01,0.99))
        const float logp  = __logf(p_obj);
        const float log1p = __logf(1.0f - p_obj);

        const float bce_obj = -(iou * logp + (1.0f - iou) * log1p);

        // 3-class log-softmax CE
        const float mx = fmaxf(fmaxf(l0, l1), l2);
        const float esum = __expf(l0 - mx) + __expf(l1 - mx) + __expf(l2 - mx);
        const float lse = mx + __logf(esum);
        const float lcls = (cls < 0.5f) ? l0 : ((cls < 1.5f) ? l1 : l2);
        const float ce = lse - lcls;

        const float bce_noobj = -(t_obj * logp + (1.0f - t_obj) * log1p);

        acc += m * (5.0f * box + 2.0f * ce + bce_obj)
             + 1.5f * (1.0f - m) * bce_noobj;
    }

    // block reduce
#pragma unroll
    for (int off = 32; off > 0; off >>= 1) acc += __shfl_down(acc, off);
    __shared__ float wsum[BLOCK / 64];
    if ((t & 63) == 0) wsum[t >> 6] = acc;
    __syncthreads();
    if (t == 0) {
        // single relaxed device atomic per block -- no fences, no L2 flush
        atomicAdd(result, wsum[0] + wsum[1] + wsum[2] + wsum[3]);
    }
}

extern "C" void kernel_launch(void* const* d_in, const int* in_sizes, int n_in,
                              void* d_out, int out_size, void* d_ws, size_t ws_size,
                              hipStream_t stream) {
    const float* out = (const float*)d_in[0];  // output [B,N,7]
    const float* tgt = (const float*)d_in[1];  // target [B,N,7]
    float* result = (float*)d_out;

    // zero the accumulator each call (d_out poisoned once before timing and
    // accumulated into by the kernel) -- async memset is graph-legal
    hipMemsetAsync(result, 0, sizeof(float), stream);

    loss_kernel<<<GRID, BLOCK, 0, stream>>>(out, tgt, result);
}

// Round 7
// 46.206 us; speedup vs baseline: 2.0574x; 1.3483x over previous
//
#include <hip/hip_runtime.h>
#include <hip/hip_bf16.h>

// Problem: B=256, N=16384, D=7, NUM_CLASSES=3, EPS=1e-6
// Inputs (float32): output [B,N,7], target [B,N,7]. Output: scalar float32.
//
// R1's fabric-roofline main loop + fused tail via HIERARCHICAL scattered
// atomics: 64 value slots on 64 distinct 128B lines (32 adds each), 64
// group counters, 1 super counter (64 adds). Avoids both proven failure
// modes: no ACQ_REL fences (R4: L2 writeback storm), no 2048 same-address
// RMWs (R5: atomic-unit serialization).

#define RD 7
#define NRECTOT (256 * 16384)            // 4,194,304 records
#define BLOCK 256
#define GRID 2048                        // 8 iterations per block, exact
#define F4T ((BLOCK * RD) / 4)           // 448 float4 per tensor per tile
#define NGRP 64
#define BLOCKS_PER_GRP (GRID / NGRP)     // 32

struct __align__(128) Group {
    float vsum;
    unsigned int cnt;
    char pad[120];
};

__global__ __launch_bounds__(BLOCK) void loss_kernel(
    const float* __restrict__ out, const float* __restrict__ tgt,
    Group* __restrict__ grp, unsigned int* __restrict__ super_cnt,
    float* __restrict__ result) {
    __shared__ float4 so4[F4T];
    __shared__ float4 st4[F4T];
    const float* so = (const float*)so4;
    const float* st = (const float*)st4;
    const float4* og = (const float4*)out;
    const float4* tg = (const float4*)tgt;

    float acc = 0.0f;
    const int t = threadIdx.x;

    for (int base = blockIdx.x * BLOCK; base < NRECTOT; base += GRID * BLOCK) {
        const int gbase4 = (base * RD) >> 2;   // base*7 divisible by 4
        __syncthreads();  // previous tile's LDS readers done

        so4[t] = og[gbase4 + t];
        st4[t] = tg[gbase4 + t];
        {
            const int idx = BLOCK + t;
            if (idx < F4T) {
                so4[idx] = og[gbase4 + idx];
                st4[idx] = tg[gbase4 + idx];
            }
        }
        __syncthreads();

        // One record per thread; stride-7 LDS is conflict-free (gcd(7,32)=1).
        const float* ro = &so[t * RD];
        const float* rt = &st[t * RD];

        const float p_obj = ro[0];
        const float px = ro[1], py = ro[2], ps = ro[3];
        const float l0 = ro[4], l1 = ro[5], l2 = ro[6];
        const float t_obj = rt[0];
        const float tx = rt[1], ty = rt[2], ts = rt[3];
        const float cls = rt[4];

        const float m = (t_obj > 0.5f) ? 1.0f : 0.0f;

        const float dx = tx - px, dy = ty - py;
        const float dsz = __fsqrt_rn(ts) - __fsqrt_rn(ps);
        const float box = dx * dx + dy * dy + 2.0f * dsz * dsz;

        const float hp = 0.5f * ps, ht = 0.5f * ts;
        const float lx = fmaxf(px - hp, tx - ht);
        const float rx = fminf(px + hp, tx + ht);
        const float ly = fmaxf(py - hp, ty - ht);
        const float ry = fminf(py + hp, ty + ht);
        const float inter = fmaxf(rx - lx, 0.0f) * fmaxf(ry - ly, 0.0f);
        const float uni = ps * ps + ts * ts - inter;
        const float iou = inter / (uni + 1e-6f);

        const float logp  = __logf(p_obj);
        const float log1p = __logf(1.0f - p_obj);

        const float bce_obj = -(iou * logp + (1.0f - iou) * log1p);

        const float mx = fmaxf(fmaxf(l0, l1), l2);
        const float esum = __expf(l0 - mx) + __expf(l1 - mx) + __expf(l2 - mx);
        const float lse = mx + __logf(esum);
        const float lcls = (cls < 0.5f) ? l0 : ((cls < 1.5f) ? l1 : l2);
        const float ce = lse - lcls;

        const float bce_noobj = -(t_obj * logp + (1.0f - t_obj) * log1p);

        acc += m * (5.0f * box + 2.0f * ce + bce_obj)
             + 1.5f * (1.0f - m) * bce_noobj;
    }

    // block reduce
#pragma unroll
    for (int off = 32; off > 0; off >>= 1) acc += __shfl_down(acc, off);
    __shared__ float wsum[BLOCK / 64];
    __shared__ bool amLast;
    if ((t & 63) == 0) wsum[t >> 6] = acc;
    __syncthreads();
    if (t == 0) {
        const float s = wsum[0] + wsum[1] + wsum[2] + wsum[3];
        const int g = blockIdx.x & (NGRP - 1);
        bool last = false;
        // scattered value add: 32 adds per address, 64 distinct lines
        atomicAdd(&grp[g].vsum, s);
        // ensure vsum add is ack'd before the counter add (per-block order)
        asm volatile("s_waitcnt vmcnt(0)" ::: "memory");
        unsigned int old = atomicAdd(&grp[g].cnt, 1u);
        if (old == BLOCKS_PER_GRP - 1) {
            // group complete; counter add already ack'd (we consumed `old`)
            unsigned int o2 = atomicAdd(super_cnt, 1u);  // 64 adds total
            last = (o2 == NGRP - 1);
        }
        amLast = last;
    }
    __syncthreads();
    if (amLast && t < NGRP) {
        // all 64 group sums are final; read at coherent point (no fences)
        float v = __hip_atomic_load(&grp[t].vsum, __ATOMIC_RELAXED,
                                    __HIP_MEMORY_SCOPE_AGENT);
#pragma unroll
        for (int off = 32; off > 0; off >>= 1) v += __shfl_down(v, off);
        if (t == 0) result[0] = v;
    }
}

extern "C" void kernel_launch(void* const* d_in, const int* in_sizes, int n_in,
                              void* d_out, int out_size, void* d_ws, size_t ws_size,
                              hipStream_t stream) {
    const float* out = (const float*)d_in[0];  // output [B,N,7]
    const float* tgt = (const float*)d_in[1];  // target [B,N,7]
    float* result = (float*)d_out;

    // d_ws: 64 Group (128B each) + super counter; zero it each call
    Group* grp = (Group*)d_ws;
    unsigned int* super_cnt = (unsigned int*)((char*)d_ws + NGRP * sizeof(Group));
    hipMemsetAsync(d_ws, 0, NGRP * sizeof(Group) + 128, stream);

    loss_kernel<<<GRID, BLOCK, 0, stream>>>(out, tgt, grp, super_cnt, result);
}

// Round 8
// 43.103 us; speedup vs baseline: 2.2055x; 1.0720x over previous
//
#include <hip/hip_runtime.h>
#include <hip/hip_bf16.h>

// Problem: B=256, N=16384, D=7, NUM_CLASSES=3, EPS=1e-6
// Inputs (float32): output [B,N,7], target [B,N,7]. Output: scalar float32.
//
// FINAL (reverted to best-known, R1): two-kernel structure.
//   kernel1: float4-staged LDS tiles, one record/thread, block reduce ->
//            2048 partials. Streams 235 MB at ~6.35 TB/s blended HBM+L3
//            (fabric roofline; invariant across 3 load structures tested).
//   kernel2: deterministic 1-block final reduce (~2 us).
// Fusion attempts all regressed (R4 agent-fence L2 storms -2x; R5 single-
// address atomic serialization -50%; R6 hierarchical scattered atomics -9%).

#define RD 7
#define NRECTOT (256 * 16384)            // 4,194,304 records
#define BLOCK 256
#define GRID 2048                        // 8 iterations per block, exact
#define F4T ((BLOCK * RD) / 4)           // 448 float4 per tensor per tile

__global__ __launch_bounds__(BLOCK) void loss_partial_kernel(
    const float* __restrict__ out, const float* __restrict__ tgt,
    float* __restrict__ partial) {
    __shared__ float4 so4[F4T];
    __shared__ float4 st4[F4T];
    const float* so = (const float*)so4;
    const float* st = (const float*)st4;
    const float4* og = (const float4*)out;
    const float4* tg = (const float4*)tgt;

    float acc = 0.0f;
    const int t = threadIdx.x;

    for (int base = blockIdx.x * BLOCK; base < NRECTOT; base += GRID * BLOCK) {
        // base*RD is always a multiple of 1792 -> divisible by 4.
        const int gbase4 = (base * RD) >> 2;
        __syncthreads();  // previous tile's LDS readers done

        // Stage 448 float4 per tensor, fully coalesced dwordx4.
        so4[t] = og[gbase4 + t];
        st4[t] = tg[gbase4 + t];
        {
            const int idx = BLOCK + t;
            if (idx < F4T) {
                so4[idx] = og[gbase4 + idx];
                st4[idx] = tg[gbase4 + idx];
            }
        }
        __syncthreads();

        // One record per thread. Stride-7 LDS: gcd(7,32)=1 -> conflict-free
        // within 32 lanes; the 2-way 64-lane aliasing is free (m136).
        const float* ro = &so[t * RD];
        const float* rt = &st[t * RD];

        const float p_obj = ro[0];
        const float px = ro[1], py = ro[2], ps = ro[3];
        const float l0 = ro[4], l1 = ro[5], l2 = ro[6];
        const float t_obj = rt[0];
        const float tx = rt[1], ty = rt[2], ts = rt[3];
        const float cls = rt[4];

        const float m = (t_obj > 0.5f) ? 1.0f : 0.0f;

        // box regression
        const float dx = tx - px, dy = ty - py;
        const float dsz = __fsqrt_rn(ts) - __fsqrt_rn(ps);
        const float box = dx * dx + dy * dy + 2.0f * dsz * dsz;

        // IoU of axis-aligned squares
        const float hp = 0.5f * ps, ht = 0.5f * ts;
        const float lx = fmaxf(px - hp, tx - ht);
        const float rx = fminf(px + hp, tx + ht);
        const float ly = fmaxf(py - hp, ty - ht);
        const float ry = fminf(py + hp, ty + ht);
        const float inter = fmaxf(rx - lx, 0.0f) * fmaxf(ry - ly, 0.0f);
        const float uni = ps * ps + ts * ts - inter;
        const float iou = inter / (uni + 1e-6f);

        // shared log terms (p_obj in (0.01,0.99))
        const float logp  = __logf(p_obj);
        const float log1p = __logf(1.0f - p_obj);

        const float bce_obj = -(iou * logp + (1.0f - iou) * log1p);

        // 3-class log-softmax CE
        const float mx = fmaxf(fmaxf(l0, l1), l2);
        const float esum = __expf(l0 - mx) + __expf(l1 - mx) + __expf(l2 - mx);
        const float lse = mx + __logf(esum);
        const float lcls = (cls < 0.5f) ? l0 : ((cls < 1.5f) ? l1 : l2);
        const float ce = lse - lcls;

        const float bce_noobj = -(t_obj * logp + (1.0f - t_obj) * log1p);

        acc += m * (5.0f * box + 2.0f * ce + bce_obj)
             + 1.5f * (1.0f - m) * bce_noobj;
    }

    // wave reduce (64 lanes)
#pragma unroll
    for (int off = 32; off > 0; off >>= 1) acc += __shfl_down(acc, off);

    __shared__ float wsum[BLOCK / 64];
    if ((t & 63) == 0) wsum[t >> 6] = acc;
    __syncthreads();
    if (t == 0)
        partial[blockIdx.x] = wsum[0] + wsum[1] + wsum[2] + wsum[3];
}

__global__ __launch_bounds__(BLOCK) void reduce_final_kernel(
    const float* __restrict__ partial, float* __restrict__ outp, int n) {
    float a = 0.0f;
    for (int i = threadIdx.x; i < n; i += BLOCK) a += partial[i];
#pragma unroll
    for (int off = 32; off > 0; off >>= 1) a += __shfl_down(a, off);
    __shared__ float wsum[BLOCK / 64];
    if ((threadIdx.x & 63) == 0) wsum[threadIdx.x >> 6] = a;
    __syncthreads();
    if (threadIdx.x == 0)
        outp[0] = wsum[0] + wsum[1] + wsum[2] + wsum[3];
}

extern "C" void kernel_launch(void* const* d_in, const int* in_sizes, int n_in,
                              void* d_out, int out_size, void* d_ws, size_t ws_size,
                              hipStream_t stream) {
    const float* out = (const float*)d_in[0];  // output [B,N,7]
    const float* tgt = (const float*)d_in[1];  // target [B,N,7]
    float* partial = (float*)d_ws;             // GRID floats of scratch
    float* result = (float*)d_out;

    loss_partial_kernel<<<GRID, BLOCK, 0, stream>>>(out, tgt, partial);
    reduce_final_kernel<<<1, BLOCK, 0, stream>>>(partial, result, GRID);
}